// Round 1
// baseline (7360.075 us; speedup 1.0000x reference)
//
#include <hip/hip_runtime.h>
#include <cmath>

typedef __attribute__((ext_vector_type(8))) short short8;
typedef __attribute__((ext_vector_type(4))) float f32x4;
typedef __attribute__((ext_vector_type(2))) unsigned short us2;
typedef unsigned long long u64;
typedef unsigned int u32;

#define SR 2184   // LDS A row stride in bf16 elements (2176 data + 8 pad to break bank aliasing)

__device__ __forceinline__ unsigned short f2bf(float x){
  u32 u = __float_as_uint(x);
  u32 r = u + 0x7FFFu + ((u >> 16) & 1u);   // round-to-nearest-even bf16
  return (unsigned short)(r >> 16);
}

// Pre-swizzle [w_res ; w_in] (K=2176 x 2048 cols) into bf16 MFMA B-fragment order:
// layout [block g][wave w][frag f][lane l][j0..7], chunk c = w*17+f covers k = c*32 + (l>>4)*8 + j,
// col = g*16 + (l&15).  557056 threads = 2176 blocks x 256.
__global__ void bswz_kernel(const float* __restrict__ wres,
                            const float* __restrict__ win,
                            unsigned short* __restrict__ B){
  int tid = blockIdx.x * 256 + threadIdx.x;
  int l  = tid & 63;
  int cf = tid >> 6;          // (g*4+w)*17 + f
  int f  = cf % 17;
  int gw = cf / 17;
  int g  = gw >> 2;
  int w  = gw & 3;
  int c  = w * 17 + f;
  int col = (g << 4) + (l & 15);
  int k0  = (c << 5) + ((l >> 4) << 3);
  short8 vv;
  #pragma unroll
  for (int j = 0; j < 8; ++j){
    int k = k0 + j;
    float v = (k < 2048) ? wres[(size_t)k * 2048 + col]
                         : win[(size_t)(k - 2048) * 2048 + col];
    vv[j] = (short)f2bf(v);
  }
  *((short8*)(B + (size_t)tid * 8)) = vv;
}

// out[b][t][0:128] = inputs  (concat head).  262144 float4s = 1024 blocks x 256.
__global__ void copy_in_kernel(const float* __restrict__ in, float* __restrict__ out){
  int i = blockIdx.x * 256 + threadIdx.x;
  int bt = i >> 5;
  int d4 = i & 31;
  float4 v = ((const float4*)in)[i];
  ((float4*)(out + (size_t)bt * 2176))[d4] = v;
}

// Persistent ESN scan. 128 blocks x 256 threads; block g owns output columns [g*16, g*16+16).
// State exchanged via tagged u64 entries: {tag=step, bf16 pair}, double-buffered by step parity.
__global__ void __launch_bounds__(256, 1) esn_persist(
    const float* __restrict__ inputs,
    const float* __restrict__ b_in,
    const unsigned short* __restrict__ Bsw,
    u64* __restrict__ ex,          // ex[2][8192] tagged state entries
    float* __restrict__ out)
{
  __shared__ __align__(16) unsigned short A[8 * SR];  // A operand: rows b=0..7, k: [0,2048) state, [2048,2176) x_t
  __shared__ __align__(16) float red[384];            // cross-wave partial reduce (waves 1..3)

  const int tid  = threadIdx.x;
  const int g    = blockIdx.x;
  const int wv   = tid >> 6;
  const int l    = tid & 63;
  const int m16  = l & 15;
  const int q    = l >> 4;
  const int col0 = g << 4;
  const int b_row = tid >> 5;   // staging row 0..7
  const int seg   = tid & 31;

  // B fragments live in registers for the whole scan (17 per wave, K split across 4 waves)
  short8 Bf[17];
  {
    const short8* bp = (const short8*)Bsw + (size_t)((g << 2) + wv) * 17 * 64 + l;
    #pragma unroll
    for (int f = 0; f < 17; ++f) Bf[f] = bp[f * 64];
  }
  const float bias = b_in[col0 + m16];
  float s_loc[4] = {0.f, 0.f, 0.f, 0.f};   // fp32 leak-path state (wave0 lanes<32)

  for (int t = 0; t < 1024; ++t){
    // ---- stage x_t (no dependency on other blocks) ----
    {
      const float4* xs = (const float4*)(inputs + ((size_t)b_row * 1024 + t) * 128);
      float4 xv = xs[seg];
      unsigned short* dx = &A[b_row * SR + 2048 + (seg << 2)];
      dx[0] = f2bf(xv.x); dx[1] = f2bf(xv.y); dx[2] = f2bf(xv.z); dx[3] = f2bf(xv.w);
    }
    // ---- stage s_t via tagged entries: issue all 32 loads, then check/retry ----
    {
      u64* srcb = ex + (size_t)(t & 1) * 8192;
      const u32 want = (u32)t;
      u64 v[32];
      #pragma unroll
      for (int i = 0; i < 32; ++i)
        v[i] = __hip_atomic_load(&srcb[i * 256 + tid], __ATOMIC_RELAXED, __HIP_MEMORY_SCOPE_AGENT);
      #pragma unroll
      for (int i = 0; i < 32; ++i){
        int e = i * 256 + tid;
        while ((u32)(v[i] >> 32) != want)
          v[i] = __hip_atomic_load(&srcb[e], __ATOMIC_RELAXED, __HIP_MEMORY_SCOPE_AGENT);
        int b  = e >> 10;
        int u0 = (e & 1023) << 1;
        us2 pr = { (unsigned short)(v[i] & 0xFFFFu), (unsigned short)((v[i] >> 16) & 0xFFFFu) };
        *((us2*)&A[b * SR + u0]) = pr;
      }
    }
    __syncthreads();

    // ---- MFMA: K=2176 split 4 ways across waves, 17 x 16x16x32 each ----
    f32x4 acc = {0.f, 0.f, 0.f, 0.f};
    {
      const unsigned short* Ab = &A[(m16 & 7) * SR + (q << 3)];
      #pragma unroll
      for (int f = 0; f < 17; ++f){
        int c = wv * 17 + f;
        short8 a = {0,0,0,0,0,0,0,0};
        if (m16 < 8) a = *((const short8*)(Ab + (c << 5)));   // rows m>=8 are zero
        acc = __builtin_amdgcn_mfma_f32_16x16x32_bf16(a, Bf[f], acc, 0, 0, 0);
      }
    }
    if (wv > 0 && l < 32)
      *((f32x4*)&red[((wv - 1) << 7) + (l << 2)]) = acc;
    __syncthreads();

    // ---- wave0: reduce, tanh, leak, publish ----
    if (wv == 0 && l < 32){
      f32x4 p = acc;
      #pragma unroll
      for (int w = 0; w < 3; ++w) p += *((const f32x4*)&red[(w << 7) + (l << 2)]);
      u64* exw = ex + (size_t)((t + 1) & 1) * 8192;
      const int u = col0 + m16;
      #pragma unroll
      for (int r = 0; r < 4; ++r){
        float pre = p[r] + bias;
        float nv = 0.5f * s_loc[r] + 0.5f * tanhf(pre);
        s_loc[r] = nv;
        int mm = (q << 2) + r;                         // batch row 0..7
        float pw = (u & 1) ? nv : nv * nv;             // PowerIndex: even u squared
        out[((size_t)(mm << 10) + t) * 2176 + 128 + u] = pw;
        float pv = __shfl_xor(nv, 1);                  // partner column's value
        if (!(u & 1)){
          u64 eval = ((u64)(u32)(t + 1) << 32) | ((u32)f2bf(pv) << 16) | (u32)f2bf(nv);
          __hip_atomic_store(&exw[(mm << 10) + (u >> 1)], eval,
                             __ATOMIC_RELAXED, __HIP_MEMORY_SCOPE_AGENT);
        }
      }
    }
    __syncthreads();   // protect red/A before next iteration's staging
  }
}

extern "C" void kernel_launch(void* const* d_in, const int* in_sizes, int n_in,
                              void* d_out, int out_size, void* d_ws, size_t ws_size,
                              hipStream_t stream){
  const float* inputs = (const float*)d_in[0];   // [8,1024,128]
  const float* w_in   = (const float*)d_in[1];   // [128,2048]
  const float* b_in   = (const float*)d_in[2];   // [2048]
  const float* w_res  = (const float*)d_in[3];   // [2048,2048]
  float* out = (float*)d_out;

  u64* ex = (u64*)d_ws;                                        // 2*8192*8 = 131072 B
  unsigned short* Bsw = (unsigned short*)((char*)d_ws + 131072); // 8,912,896 B swizzled weights

  // zero tags+values: tag 0 == "s_0 = 0 ready"
  hipMemsetAsync(d_ws, 0, 131072, stream);
  bswz_kernel<<<2176, 256, 0, stream>>>(w_res, w_in, Bsw);
  copy_in_kernel<<<1024, 256, 0, stream>>>(inputs, out);
  esn_persist<<<128, 256, 0, stream>>>(inputs, b_in, Bsw, ex, out);
}

// Round 2
// 4184.093 us; speedup vs baseline: 1.7591x; 1.7591x over previous
//
#include <hip/hip_runtime.h>
#include <cmath>

typedef __attribute__((ext_vector_type(8))) short short8;
typedef __attribute__((ext_vector_type(4))) float f32x4;
typedef __attribute__((ext_vector_type(2))) unsigned short us2;
typedef unsigned long long u64;
typedef unsigned int u32;

#define SR 2184   // LDS A row stride in bf16 elements (2176 data + 8 pad)

__device__ __forceinline__ unsigned short f2bf(float x){
  u32 u = __float_as_uint(x);
  u32 r = u + 0x7FFFu + ((u >> 16) & 1u);   // round-to-nearest-even bf16
  return (unsigned short)(r >> 16);
}

// Pre-swizzle [w_res ; w_in] (K=2176 x 2048 cols) into bf16 MFMA B-fragment order:
// layout [G][ks][frag f][lane l][j0..7], chunk c = ks*17+f covers k = c*32 + (l>>4)*8 + j,
// col = G*16 + (l&15).  G = 0..127 column-group, ks = 0..3 K-split.
__global__ void bswz_kernel(const float* __restrict__ wres,
                            const float* __restrict__ win,
                            unsigned short* __restrict__ B){
  int tid = blockIdx.x * 256 + threadIdx.x;
  int l  = tid & 63;
  int cf = tid >> 6;          // (G*4+ks)*17 + f
  int f  = cf % 17;
  int gw = cf / 17;
  int ks = gw & 3;
  int G  = gw >> 2;
  int c  = ks * 17 + f;
  int col = (G << 4) + (l & 15);
  int k0  = (c << 5) + ((l >> 4) << 3);
  short8 vv;
  #pragma unroll
  for (int j = 0; j < 8; ++j){
    int k = k0 + j;
    float v = (k < 2048) ? wres[(size_t)k * 2048 + col]
                         : win[(size_t)(k - 2048) * 2048 + col];
    vv[j] = (short)f2bf(v);
  }
  *((short8*)(B + (size_t)tid * 8)) = vv;
}

// out[b][t][0:128] = inputs  (concat head).  262144 float4s = 1024 blocks x 256.
__global__ void copy_in_kernel(const float* __restrict__ in, float* __restrict__ out){
  int i = blockIdx.x * 256 + threadIdx.x;
  int bt = i >> 5;
  int d4 = i & 31;
  float4 v = ((const float4*)in)[i];
  ((float4*)(out + (size_t)bt * 2176))[d4] = v;
}

// Persistent ESN scan. 64 blocks x 512 threads; block g owns columns [g*32, g*32+32)
// as two 16-col groups (cg=0,1); waves: wv = cg*4 + ks (K split 4 ways per group).
// State exchanged via tagged u64 entries {tag=step, bf16 pair}, double-buffered by parity.
// Consumer polls in BATCHED rounds (issue all pending loads, then check) — round 1's
// per-entry serial while-loop was the 10 us/step bottleneck (32 serial L3 round trips).
__global__ void __launch_bounds__(512, 1) esn_persist(
    const float* __restrict__ inputs,
    const float* __restrict__ b_in,
    const unsigned short* __restrict__ Bsw,
    u64* __restrict__ ex,          // ex[2][8192] tagged state entries
    float* __restrict__ out)
{
  __shared__ __align__(16) unsigned short A[8 * SR];  // rows b=0..7, k: [0,2048) state, [2048,2176) x_t
  __shared__ __align__(16) float red[768];            // cross-wave partial reduce: [cg][ks-1][128]

  const int tid  = threadIdx.x;
  const int g    = blockIdx.x;     // 0..63
  const int wv   = tid >> 6;       // 0..7
  const int l    = tid & 63;
  const int m16  = l & 15;
  const int q    = l >> 4;
  const int cg   = wv >> 2;        // column-group 0/1
  const int ks   = wv & 3;         // K-split 0..3
  const int G    = (g << 1) + cg;  // global 16-col group 0..127
  const int col0 = G << 4;

  // B fragments in registers for the whole scan (17 per wave)
  short8 Bf[17];
  {
    const short8* bp = (const short8*)Bsw + (size_t)((G << 2) + ks) * 17 * 64 + l;
    #pragma unroll
    for (int f = 0; f < 17; ++f) Bf[f] = bp[f * 64];
  }
  const float bias = b_in[col0 + m16];
  float s_loc[4] = {0.f, 0.f, 0.f, 0.f};   // fp32 leak-path state (ks==0 waves, lanes<32)

  for (int t = 0; t < 1024; ++t){
    // ---- stage x_t (no cross-block dependency; overlaps the poll below) ----
    if (tid < 256){
      const int b_row = tid >> 5;
      const int seg   = tid & 31;
      const float4* xs = (const float4*)(inputs + ((size_t)b_row * 1024 + t) * 128);
      float4 xv = xs[seg];
      unsigned short* dx = &A[b_row * SR + 2048 + (seg << 2)];
      dx[0] = f2bf(xv.x); dx[1] = f2bf(xv.y); dx[2] = f2bf(xv.z); dx[3] = f2bf(xv.w);
    }
    // ---- stage s_t: batched tagged-poll rounds, 16 entries/thread ----
    {
      u64* srcb = ex + (size_t)(t & 1) * 8192;
      const u32 want = (u32)t;
      u32 pend = 0xFFFFu;
      u64 v[16];
      while (pend){
        #pragma unroll
        for (int i = 0; i < 16; ++i)
          if (pend & (1u << i))
            v[i] = __hip_atomic_load(&srcb[i * 512 + tid], __ATOMIC_RELAXED, __HIP_MEMORY_SCOPE_AGENT);
        u32 np = 0;
        #pragma unroll
        for (int i = 0; i < 16; ++i)
          if (pend & (1u << i)){
            if ((u32)(v[i] >> 32) == want){
              int e  = i * 512 + tid;
              int b  = e >> 10;
              int u0 = (e & 1023) << 1;
              us2 pr = { (unsigned short)(v[i] & 0xFFFFu), (unsigned short)((v[i] >> 16) & 0xFFFFu) };
              *((us2*)&A[b * SR + u0]) = pr;
            } else np |= (1u << i);
          }
        pend = np;
      }
    }
    __syncthreads();

    // ---- MFMA: K=2176 split 4 ways, 17 x 16x16x32 per wave ----
    f32x4 acc = {0.f, 0.f, 0.f, 0.f};
    {
      const unsigned short* Ab = &A[(m16 & 7) * SR + (q << 3)];
      #pragma unroll
      for (int f = 0; f < 17; ++f){
        int c = ks * 17 + f;
        short8 a = {0,0,0,0,0,0,0,0};
        if (m16 < 8) a = *((const short8*)(Ab + (c << 5)));   // rows m>=8 are zero
        acc = __builtin_amdgcn_mfma_f32_16x16x32_bf16(a, Bf[f], acc, 0, 0, 0);
      }
    }
    if (ks > 0 && l < 32)
      *((f32x4*)&red[cg * 384 + ((ks - 1) << 7) + (l << 2)]) = acc;
    __syncthreads();

    // ---- ks==0 wave of each col-group: reduce, tanh, leak, publish (publish FIRST) ----
    if (ks == 0 && l < 32){
      f32x4 p = acc;
      #pragma unroll
      for (int w = 0; w < 3; ++w) p += *((const f32x4*)&red[cg * 384 + (w << 7) + (l << 2)]);
      u64* exw = ex + (size_t)((t + 1) & 1) * 8192;
      const int u = col0 + m16;
      float nvv[4];
      #pragma unroll
      for (int r = 0; r < 4; ++r){
        float pre = p[r] + bias;
        float nv = 0.5f * s_loc[r] + 0.5f * tanhf(pre);
        s_loc[r] = nv;
        nvv[r] = nv;
        float pv = __shfl_xor(nv, 1);                  // partner column's value
        if (!(u & 1)){
          int mm = (q << 2) + r;                       // batch row 0..7
          u64 eval = ((u64)(u32)(t + 1) << 32) | ((u32)f2bf(pv) << 16) | (u32)f2bf(nv);
          __hip_atomic_store(&exw[(mm << 10) + (u >> 1)], eval,
                             __ATOMIC_RELAXED, __HIP_MEMORY_SCOPE_AGENT);
        }
      }
      #pragma unroll
      for (int r = 0; r < 4; ++r){
        int mm = (q << 2) + r;
        float nv = nvv[r];
        float pw = (u & 1) ? nv : nv * nv;             // PowerIndex: even u squared
        out[((size_t)(mm << 10) + t) * 2176 + 128 + u] = pw;
      }
    }
    __syncthreads();   // protect red/A before next iteration's staging
  }
}

extern "C" void kernel_launch(void* const* d_in, const int* in_sizes, int n_in,
                              void* d_out, int out_size, void* d_ws, size_t ws_size,
                              hipStream_t stream){
  const float* inputs = (const float*)d_in[0];   // [8,1024,128]
  const float* w_in   = (const float*)d_in[1];   // [128,2048]
  const float* b_in   = (const float*)d_in[2];   // [2048]
  const float* w_res  = (const float*)d_in[3];   // [2048,2048]
  float* out = (float*)d_out;

  u64* ex = (u64*)d_ws;                                          // 2*8192*8 = 131072 B
  unsigned short* Bsw = (unsigned short*)((char*)d_ws + 131072); // 8,912,896 B swizzled weights

  // zero tags+values: tag 0 == "s_0 = 0 ready"
  hipMemsetAsync(d_ws, 0, 131072, stream);
  bswz_kernel<<<2176, 256, 0, stream>>>(w_res, w_in, Bsw);
  copy_in_kernel<<<1024, 256, 0, stream>>>(inputs, out);
  esn_persist<<<64, 512, 0, stream>>>(inputs, b_in, Bsw, ex, out);
}

// Round 3
// 3158.897 us; speedup vs baseline: 2.3300x; 1.3245x over previous
//
#include <hip/hip_runtime.h>
#include <cmath>

typedef __attribute__((ext_vector_type(8))) short short8;
typedef __attribute__((ext_vector_type(4))) float f32x4;
typedef __attribute__((ext_vector_type(2))) unsigned short us2;
typedef unsigned long long u64;
typedef unsigned int u32;

__device__ __forceinline__ unsigned short f2bf(float x){
  u32 u = __float_as_uint(x);
  u32 r = u + 0x7FFFu + ((u >> 16) & 1u);   // round-to-nearest-even bf16
  return (unsigned short)(r >> 16);
}

// Pre-swizzle [w_res ; w_in] (K=2176 x 2048 cols) into bf16 MFMA B-fragment order.
// Layout: [gcg 0..127][ks 0..1][f 0..33][lane 0..63][j 0..7]:
//   k = ks*1088 + f*32 + (l>>4)*8 + j, col = gcg*16 + (l&15).
// 557056 threads = 2176 blocks x 256; each writes one short8.
__global__ void bswz_kernel(const float* __restrict__ wres,
                            const float* __restrict__ win,
                            unsigned short* __restrict__ B){
  int tid = blockIdx.x * 256 + threadIdx.x;
  int l   = tid & 63;
  int cf  = tid >> 6;          // (gcg*2+ks)*34 + f
  int f   = cf % 34;
  int gk  = cf / 34;
  int ks  = gk & 1;
  int gcg = gk >> 1;
  int col = (gcg << 4) + (l & 15);
  int k0  = ks * 1088 + (f << 5) + ((l >> 4) << 3);
  short8 vv;
  #pragma unroll
  for (int j = 0; j < 8; ++j){
    int k = k0 + j;
    float v = (k < 2048) ? wres[(size_t)k * 2048 + col]
                         : win[(size_t)(k - 2048) * 2048 + col];
    vv[j] = (short)f2bf(v);
  }
  *((short8*)(B + (size_t)tid * 8)) = vv;
}

// out[b][t][0:128] = inputs  (concat head).  262144 float4s = 1024 blocks x 256.
__global__ void copy_in_kernel(const float* __restrict__ in, float* __restrict__ out){
  int i = blockIdx.x * 256 + threadIdx.x;
  int bt = i >> 5;
  int d4 = i & 31;
  float4 v = ((const float4*)in)[i];
  ((float4*)(out + (size_t)bt * 2176))[d4] = v;
}

// Persistent ESN scan, BATCH-SPLIT: the 8 batch rows are independent recurrences.
// 128 blocks x 512 threads = 4 row-pairs x 32 col-blocks; block owns 64 columns
// x 2 batch rows (MFMA M=2, rows 2..15 zero). Each block only exchanges its own
// 2 rows' state: 16 KB/round payload (vs 64 KB in round 2), 4 polled entries/thread.
// Exchange: tagged u64 {tag=step, bf16 odd-col, bf16 even-col}, per-row buffers of
// 1024 entries, double-buffered by step parity.
__global__ void __launch_bounds__(512, 2) esn_persist(
    const float* __restrict__ inputs,
    const float* __restrict__ b_in,
    const unsigned short* __restrict__ Bsw,
    u64* __restrict__ ex,          // ex[parity 2][row 8][1024 entries]
    float* __restrict__ out)
{
  __shared__ __align__(16) unsigned short As[2 * 2176];  // [row 0/1][k: 2048 state + 128 x_t]
  __shared__ float red[2][4][16][2];                     // [parity][cg][m16][row]

  const int tid = threadIdx.x;
  const int blk = blockIdx.x;      // 0..127
  const int r0  = (blk >> 5) << 1; // batch rows {r0, r0+1}
  const int cb  = blk & 31;        // column block: cols [cb*64, cb*64+64)
  const int wv  = tid >> 6;        // 0..7
  const int l   = tid & 63;
  const int m16 = l & 15;
  const int q   = l >> 4;
  const int cg  = wv >> 1;         // col-group 0..3 (16 cols each)
  const int ks  = wv & 1;          // K-split 0/1 (K=1088 each)
  const int gcg = (cb << 2) + cg;  // global col-group 0..127
  const int colw0 = gcg << 4;

  // B fragments in registers for the whole scan (34 per wave = 136 VGPRs)
  short8 Bf[34];
  {
    const short8* bp = (const short8*)Bsw + (size_t)((gcg << 1) + ks) * 34 * 64 + l;
    #pragma unroll
    for (int f = 0; f < 34; ++f) Bf[f] = bp[f * 64];
  }
  const float bias = b_in[colw0 + m16];
  float s0 = 0.f, s1 = 0.f;        // fp32 leak-path state (ks==0, lanes<16)

  const float* xr0 = inputs + (size_t)r0 * 1024 * 128;

  for (int t = 0; t < 1024; ++t){
    // ---- stage x_t for both rows (no cross-block dependency) ----
    if (tid < 64){
      const int row = tid >> 5;
      const int seg = tid & 31;
      float4 xv = ((const float4*)(xr0 + ((size_t)row * 1024 + t) * 128))[seg];
      unsigned short* dx = &As[row * 2176 + 2048 + (seg << 2)];
      dx[0] = f2bf(xv.x); dx[1] = f2bf(xv.y); dx[2] = f2bf(xv.z); dx[3] = f2bf(xv.w);
    }
    // ---- stage s_t: batched tagged-poll, 4 entries/thread over rows r0,r0+1 ----
    {
      u64* srcb = ex + ((size_t)(t & 1) * 8 + r0) * 1024;   // rows r0,r0+1 contiguous
      const u32 want = (u32)t;
      u64 v[4];
      #pragma unroll
      for (int i = 0; i < 4; ++i)
        v[i] = __hip_atomic_load(&srcb[i * 512 + tid], __ATOMIC_RELAXED, __HIP_MEMORY_SCOPE_AGENT);
      u32 pend = 0xFu;
      while (pend){
        u32 np = 0;
        #pragma unroll
        for (int i = 0; i < 4; ++i)
          if (pend & (1u << i)){
            if ((u32)(v[i] >> 32) == want){
              int e = i * 512 + tid;
              us2 pr = { (unsigned short)(v[i] & 0xFFFFu), (unsigned short)((v[i] >> 16) & 0xFFFFu) };
              ((us2*)As)[(e >> 10) * 1088 + (e & 1023)] = pr;
            } else np |= (1u << i);
          }
        pend = np;
        #pragma unroll
        for (int i = 0; i < 4; ++i)
          if (pend & (1u << i))
            v[i] = __hip_atomic_load(&srcb[i * 512 + tid], __ATOMIC_RELAXED, __HIP_MEMORY_SCOPE_AGENT);
      }
    }
    __syncthreads();

    // ---- MFMA: M=2 (rows r0,r0+1), K=1088 per wave, 34 x 16x16x32, 2 acc chains ----
    f32x4 acc0 = {0.f,0.f,0.f,0.f}, acc1 = {0.f,0.f,0.f,0.f};
    {
      const unsigned short* Ab = &As[m16 * 2176 + ks * 1088 + (q << 3)];
      const bool act = (m16 < 2);
      #pragma unroll
      for (int f = 0; f < 34; f += 2){
        short8 a0 = {0,0,0,0,0,0,0,0}, a1 = {0,0,0,0,0,0,0,0};
        if (act){
          a0 = *((const short8*)(Ab + (f << 5)));
          a1 = *((const short8*)(Ab + ((f + 1) << 5)));
        }
        acc0 = __builtin_amdgcn_mfma_f32_16x16x32_bf16(a0, Bf[f],     acc0, 0, 0, 0);
        acc1 = __builtin_amdgcn_mfma_f32_16x16x32_bf16(a1, Bf[f + 1], acc1, 0, 0, 0);
      }
    }
    // C/D: col=l&15, row=q*4+reg → rows 0,1 live in lanes 0..15, regs 0,1
    float p0 = acc0[0] + acc1[0];
    float p1 = acc0[1] + acc1[1];
    if (ks == 1 && l < 16){
      red[t & 1][cg][m16][0] = p0;
      red[t & 1][cg][m16][1] = p1;
    }
    __syncthreads();

    // ---- ks==0 lanes<16: reduce, tanh, leak, publish FIRST, then out stores ----
    if (ks == 0 && l < 16){
      p0 += red[t & 1][cg][m16][0];
      p1 += red[t & 1][cg][m16][1];
      float nv0 = 0.5f * s0 + 0.5f * tanhf(p0 + bias);
      float nv1 = 0.5f * s1 + 0.5f * tanhf(p1 + bias);
      s0 = nv0; s1 = nv1;
      float pv0 = __shfl_xor(nv0, 1);
      float pv1 = __shfl_xor(nv1, 1);
      const int u = colw0 + m16;
      if (!(m16 & 1)){
        u64* exw = ex + ((size_t)((t + 1) & 1) * 8 + r0) * 1024;
        u64 e0 = ((u64)(u32)(t + 1) << 32) | ((u32)f2bf(pv0) << 16) | (u32)f2bf(nv0);
        u64 e1 = ((u64)(u32)(t + 1) << 32) | ((u32)f2bf(pv1) << 16) | (u32)f2bf(nv1);
        __hip_atomic_store(&exw[u >> 1],        e0, __ATOMIC_RELAXED, __HIP_MEMORY_SCOPE_AGENT);
        __hip_atomic_store(&exw[1024 + (u >> 1)], e1, __ATOMIC_RELAXED, __HIP_MEMORY_SCOPE_AGENT);
      }
      float pw0 = (u & 1) ? nv0 : nv0 * nv0;   // PowerIndex: even u squared
      float pw1 = (u & 1) ? nv1 : nv1 * nv1;
      out[((size_t)r0 * 1024 + t) * 2176 + 128 + u] = pw0;
      out[((size_t)(r0 + 1) * 1024 + t) * 2176 + 128 + u] = pw1;
    }
    // no third barrier: As reads finished before barrier 2; red is parity-double-buffered
  }
}

extern "C" void kernel_launch(void* const* d_in, const int* in_sizes, int n_in,
                              void* d_out, int out_size, void* d_ws, size_t ws_size,
                              hipStream_t stream){
  const float* inputs = (const float*)d_in[0];   // [8,1024,128]
  const float* w_in   = (const float*)d_in[1];   // [128,2048]
  const float* b_in   = (const float*)d_in[2];   // [2048]
  const float* w_res  = (const float*)d_in[3];   // [2048,2048]
  float* out = (float*)d_out;

  u64* ex = (u64*)d_ws;                                          // 2*8*1024*8 = 131072 B
  unsigned short* Bsw = (unsigned short*)((char*)d_ws + 131072); // 8,912,896 B swizzled weights

  // zero tags+values: tag 0 == "s_0 = 0 ready"
  hipMemsetAsync(d_ws, 0, 131072, stream);
  bswz_kernel<<<2176, 256, 0, stream>>>(w_res, w_in, Bsw);
  copy_in_kernel<<<1024, 256, 0, stream>>>(inputs, out);
  esn_persist<<<128, 512, 0, stream>>>(inputs, b_in, Bsw, ex, out);
}

// Round 4
// 3077.602 us; speedup vs baseline: 2.3915x; 1.0264x over previous
//
#include <hip/hip_runtime.h>
#include <cmath>

typedef __attribute__((ext_vector_type(8))) short short8;
typedef __attribute__((ext_vector_type(4))) float f32x4;
typedef unsigned long long u64;
typedef unsigned int u32;

#define RS 2208   // A row stride in bf16 (2176 data + 32 pad -> rows offset by 16 banks)

__device__ __forceinline__ unsigned short f2bf(float x){
  u32 u = __float_as_uint(x);
  u32 r = u + 0x7FFFu + ((u >> 16) & 1u);   // round-to-nearest-even bf16
  return (unsigned short)(r >> 16);
}

__device__ __forceinline__ float tanh_fast(float x){
  float xc = fminf(fmaxf(x, -10.f), 10.f);   // tanh(10)=1-4e-9; also keeps exp finite
  float e = __expf(2.f * xc);
  return (e - 1.f) / (e + 1.f);
}

// Pre-swizzle [w_res ; w_in] (K=2176 x 2048 cols) into bf16 MFMA B-fragment order.
// Layout: [gcg 0..127][ks 0..1][f 0..33][lane 0..63][j 0..7]:
//   k = ks*1088 + f*32 + (l>>4)*8 + j, col = gcg*16 + (l&15).
__global__ void bswz_kernel(const float* __restrict__ wres,
                            const float* __restrict__ win,
                            unsigned short* __restrict__ B){
  int tid = blockIdx.x * 256 + threadIdx.x;
  int l   = tid & 63;
  int cf  = tid >> 6;          // (gcg*2+ks)*34 + f
  int f   = cf % 34;
  int gk  = cf / 34;
  int ks  = gk & 1;
  int gcg = gk >> 1;
  int col = (gcg << 4) + (l & 15);
  int k0  = ks * 1088 + (f << 5) + ((l >> 4) << 3);
  short8 vv;
  #pragma unroll
  for (int j = 0; j < 8; ++j){
    int k = k0 + j;
    float v = (k < 2048) ? wres[(size_t)k * 2048 + col]
                         : win[(size_t)(k - 2048) * 2048 + col];
    vv[j] = (short)f2bf(v);
  }
  *((short8*)(B + (size_t)tid * 8)) = vv;
}

// out[b][t][0:128] = inputs  (concat head).  262144 float4s = 1024 blocks x 256.
__global__ void copy_in_kernel(const float* __restrict__ in, float* __restrict__ out){
  int i = blockIdx.x * 256 + threadIdx.x;
  int bt = i >> 5;
  int d4 = i & 31;
  float4 v = ((const float4*)in)[i];
  ((float4*)(out + (size_t)bt * 2176))[d4] = v;
}

// Exchange init: ex[2][8][512] u64.  Parity 0 = 0 (tag-bit 0, s_0 = 0 -> valid for t=0).
// Parity 1 = all-bf16-LSB=1 (tag-bit 1): t=1 wants bit 0 -> init rejected until real data.
__global__ void exinit_kernel(u64* __restrict__ ex){
  int i = blockIdx.x * 256 + threadIdx.x;   // 8192 entries
  ex[i] = (i < 4096) ? 0ULL : 0x0001000100010001ULL;
}

// Persistent ESN scan: 128 blocks x 512 threads = 4 row-pairs x 32 col-blocks of 64 cols.
// Exchange entries: u64 = 4 consecutive columns' bf16 with LSB = step tag-bit ((t>>1)&1).
// Double-buffered by parity; stale slot is always step t-2 whose tag-bit differs. 2 polls/thread.
__global__ void __launch_bounds__(512, 2) esn_persist(
    const float* __restrict__ inputs,
    const float* __restrict__ b_in,
    const unsigned short* __restrict__ Bsw,
    u64* __restrict__ ex,          // ex[parity 2][row 8][512 entries]
    float* __restrict__ out)
{
  __shared__ __align__(16) unsigned short As[2 * RS];  // [row 0/1][k: 2048 state + 128 x_t + pad]
  __shared__ float red[2][4][16][2];                   // [parity][cg][m16][row]

  const int tid = threadIdx.x;
  const int blk = blockIdx.x;      // 0..127
  const int r0  = (blk >> 5) << 1; // batch rows {r0, r0+1}
  const int cb  = blk & 31;        // column block: cols [cb*64, cb*64+64)
  const int wv  = tid >> 6;        // 0..7
  const int l   = tid & 63;
  const int m16 = l & 15;
  const int q   = l >> 4;
  const int cg  = wv >> 1;         // col-group 0..3 (16 cols each)
  const int ks  = wv & 1;          // K-split 0/1 (K=1088 each)
  const int gcg = (cb << 2) + cg;  // global col-group 0..127
  const int colw0 = gcg << 4;

  // B fragments in registers for the whole scan (34 per wave = 136 VGPRs)
  short8 Bf[34];
  {
    const short8* bp = (const short8*)Bsw + (size_t)((gcg << 1) + ks) * 34 * 64 + l;
    #pragma unroll
    for (int f = 0; f < 34; ++f) Bf[f] = bp[f * 64];
  }
  const float bias = b_in[colw0 + m16];
  float s0 = 0.f, s1 = 0.f;        // fp32 leak-path state (ks==0, lanes<16)

  const float* xr0 = inputs + (size_t)r0 * 1024 * 128;
  const u64 M = 0x0001000100010001ULL;

  for (int t = 0; t < 1024; ++t){
    // ---- stage x_t: 64 threads, one packed 8B LDS write each (bank-clean) ----
    if (tid < 64){
      const int row = tid >> 5;
      const int c   = tid & 31;
      float4 xv = ((const float4*)(xr0 + ((size_t)row * 1024 + t) * 128))[c];
      u64 pk = (u64)f2bf(xv.x) | ((u64)f2bf(xv.y) << 16)
             | ((u64)f2bf(xv.z) << 32) | ((u64)f2bf(xv.w) << 48);
      *((u64*)&As[row * RS + 2048 + (c << 2)]) = pk;
    }
    // ---- poll 2 tagged entries/thread (rows r0, r0+1), stage raw u64 on match ----
    {
      u64* srcb = ex + ((size_t)(t & 1) * 8 + r0) * 512;
      const u64 wantm = ((t >> 1) & 1) ? M : 0ULL;
      u64 v0 = __hip_atomic_load(&srcb[tid],       __ATOMIC_RELAXED, __HIP_MEMORY_SCOPE_AGENT);
      u64 v1 = __hip_atomic_load(&srcb[512 + tid], __ATOMIC_RELAXED, __HIP_MEMORY_SCOPE_AGENT);
      u32 pend = 3;
      while (pend){
        u32 np = 0;
        if (pend & 1){
          if ((v0 & M) == wantm) *((u64*)&As[tid << 2]) = v0;
          else np |= 1;
        }
        if (pend & 2){
          if ((v1 & M) == wantm) *((u64*)&As[RS + (tid << 2)]) = v1;
          else np |= 2;
        }
        pend = np;
        if (pend & 1) v0 = __hip_atomic_load(&srcb[tid],       __ATOMIC_RELAXED, __HIP_MEMORY_SCOPE_AGENT);
        if (pend & 2) v1 = __hip_atomic_load(&srcb[512 + tid], __ATOMIC_RELAXED, __HIP_MEMORY_SCOPE_AGENT);
      }
    }
    __syncthreads();

    // ---- MFMA: M=2, K=1088 per wave, 34 x 16x16x32, 2 interleaved acc chains.
    // Unconditional A read, row = m16&1: 8 lanes/address -> free LDS broadcast;
    // lanes m16>=2 feed garbage into D rows 2..15 which are never read.
    f32x4 acc0 = {0.f,0.f,0.f,0.f}, acc1 = {0.f,0.f,0.f,0.f};
    {
      const unsigned short* Ab = &As[(m16 & 1) * RS + ks * 1088 + (q << 3)];
      #pragma unroll
      for (int f = 0; f < 34; f += 2){
        short8 a0 = *((const short8*)(Ab + (f << 5)));
        short8 a1 = *((const short8*)(Ab + ((f + 1) << 5)));
        acc0 = __builtin_amdgcn_mfma_f32_16x16x32_bf16(a0, Bf[f],     acc0, 0, 0, 0);
        acc1 = __builtin_amdgcn_mfma_f32_16x16x32_bf16(a1, Bf[f + 1], acc1, 0, 0, 0);
      }
    }
    // C/D: col=l&15, row=q*4+reg -> batch rows 0,1 live in lanes 0..15, regs 0,1
    float p0 = acc0[0] + acc1[0];
    float p1 = acc0[1] + acc1[1];
    if (ks == 1 && l < 16){
      red[t & 1][cg][m16][0] = p0;
      red[t & 1][cg][m16][1] = p1;
    }
    __syncthreads();

    // ---- ks==0 lanes<16: reduce, tanh, leak, publish FIRST, then out stores ----
    if (ks == 0 && l < 16){
      p0 += red[t & 1][cg][m16][0];
      p1 += red[t & 1][cg][m16][1];
      float nv0 = 0.5f * s0 + 0.5f * tanh_fast(p0 + bias);
      float nv1 = 0.5f * s1 + 0.5f * tanh_fast(p1 + bias);
      s0 = nv0; s1 = nv1;
      const u32 bit = (u32)(((t + 1) >> 1) & 1);
      u32 b0 = ((u32)f2bf(nv0) & 0xFFFEu) | bit;   // tag-bit in bf16 LSB
      u32 b1 = ((u32)f2bf(nv1) & 0xFFFEu) | bit;
      // pack 4 lanes' cols into one u64 (valid on lanes m16%4==0)
      u32 pr0 = b0 | (((u32)__shfl_xor((int)b0, 1)) << 16);
      u32 pr1 = b1 | (((u32)__shfl_xor((int)b1, 1)) << 16);
      u64 e0 = (u64)pr0 | ((u64)(u32)__shfl_xor((int)pr0, 2) << 32);
      u64 e1 = (u64)pr1 | ((u64)(u32)__shfl_xor((int)pr1, 2) << 32);
      const int u = colw0 + m16;
      if ((m16 & 3) == 0){
        u64* exw = ex + ((size_t)((t + 1) & 1) * 8 + r0) * 512;
        const int p = (colw0 + m16) >> 2;
        __hip_atomic_store(&exw[p],       e0, __ATOMIC_RELAXED, __HIP_MEMORY_SCOPE_AGENT);
        __hip_atomic_store(&exw[512 + p], e1, __ATOMIC_RELAXED, __HIP_MEMORY_SCOPE_AGENT);
      }
      float pw0 = (u & 1) ? nv0 : nv0 * nv0;       // PowerIndex: even u squared
      float pw1 = (u & 1) ? nv1 : nv1 * nv1;
      out[((size_t)r0 * 1024 + t) * 2176 + 128 + u] = pw0;
      out[((size_t)(r0 + 1) * 1024 + t) * 2176 + 128 + u] = pw1;
    }
    // no third barrier: As reads complete before barrier 2; red is parity-double-buffered
  }
}

extern "C" void kernel_launch(void* const* d_in, const int* in_sizes, int n_in,
                              void* d_out, int out_size, void* d_ws, size_t ws_size,
                              hipStream_t stream){
  const float* inputs = (const float*)d_in[0];   // [8,1024,128]
  const float* w_in   = (const float*)d_in[1];   // [128,2048]
  const float* b_in   = (const float*)d_in[2];   // [2048]
  const float* w_res  = (const float*)d_in[3];   // [2048,2048]
  float* out = (float*)d_out;

  u64* ex = (u64*)d_ws;                                         // 2*8*512*8 = 65536 B
  unsigned short* Bsw = (unsigned short*)((char*)d_ws + 65536); // 8,912,896 B swizzled weights

  exinit_kernel<<<32, 256, 0, stream>>>(ex);
  bswz_kernel<<<2176, 256, 0, stream>>>(w_res, w_in, Bsw);
  copy_in_kernel<<<1024, 256, 0, stream>>>(inputs, out);
  esn_persist<<<128, 512, 0, stream>>>(inputs, b_in, Bsw, ex, out);
}